// Round 1
// 536.046 us; speedup vs baseline: 1.0874x; 1.0874x over previous
//
#include <hip/hip_runtime.h>

#define BDIM 8
#define CDIM 256
#define HDIM 96
#define WDIM 96
#define GRP  4
#define CG   64          // channels per group
#define SH   192         // s*H
#define SW   192         // s*W
#define HW   (HDIM*WDIM) // 9216

// ---------------------------------------------------------------------------
// Kernel 1: per-pixel 256->32 dot product (the 1x1 conv offset head).
// K-split by 4: block = 256 threads = 64 pixels x 4 channel-slices.
// Each wave owns one 64-channel slice (wave-uniform -> w_off stays in
// s_loads). Partials combined through LDS (pad 33 -> conflict-free).
// Grid 1152 blocks x 4 waves = 4.5 waves/SIMD (was 1.1) for latency hiding.
// Writes offsets pre-scaled by 0.25 into off, layout [B][32][H][W].
// ---------------------------------------------------------------------------
__global__ __launch_bounds__(256) void dysample_offset_kernel(
    const float* __restrict__ x,
    const float* __restrict__ w_off,
    const float* __restrict__ b_off,
    float* __restrict__ off)
{
    __shared__ float part[4][64][33];   // 33.8 KB; pad 33 -> bank-conflict-free

    int tid = threadIdx.x;
    int pix = tid & 63;
    // wave id == k-slice; readfirstlane proves uniformity to the compiler
    int ks  = __builtin_amdgcn_readfirstlane(tid >> 6);

    int p0  = blockIdx.x * 64;          // 64 | HW -> block never straddles b
    int b0  = p0 / HW;
    int hw0 = p0 - b0 * HW;
    int hw  = hw0 + pix;

    const float* xq = x + (size_t)b0 * CDIM * HW + (size_t)(ks * CG) * HW + hw;
    const float* wq = w_off + ks * CG;

    float acc[32];
    #pragma unroll
    for (int o = 0; o < 32; ++o) acc[o] = 0.0f;

    #pragma unroll 4
    for (int i = 0; i < CG; ++i) {
        float xv = xq[(size_t)i * HW];            // coalesced 256B per wave
        #pragma unroll
        for (int o = 0; o < 32; ++o)
            acc[o] = fmaf(xv, wq[o * CDIM + i], acc[o]);   // s_load (uniform)
    }

    #pragma unroll
    for (int o = 0; o < 32; ++o)
        part[ks][pix][o] = acc[o];

    __syncthreads();

    // reduce: thread -> (pix2, 8 outputs). Stores coalesced per o-plane.
    int pix2 = tid & 63;
    int og   = tid >> 6;                 // wave-uniform
    float* op = off + ((size_t)b0 * 32) * HW + hw0 + pix2;
    #pragma unroll
    for (int j = 0; j < 8; ++j) {
        int o = og * 8 + j;
        float s = part[0][pix2][o] + part[1][pix2][o]
                + part[2][pix2][o] + part[3][pix2][o];
        op[(size_t)o * HW] = (s + b_off[o]) * 0.25f;
    }
}

// ---------------------------------------------------------------------------
// Kernel 2: bilinear sampling. Block = 768 threads = 4 output rows x 192 cols
// for one (b, gi, h-tile): 3 input rows serve 4 output rows in-block
// (over-fetch 4x -> 1.5x). XCD-bijective swizzle keeps adjacent h-tiles of a
// batch on one XCD's L2. Output stores are nontemporal so the 295 MB write
// stream doesn't evict x from L2.
// ---------------------------------------------------------------------------
#define NBLK2 (BDIM * GRP * 48)   // 1536; 1536 % 8 == 0 -> simple swizzle ok
__global__ __launch_bounds__(768) void dysample_sample_kernel(
    const float* __restrict__ x,
    const float* __restrict__ off,
    float* __restrict__ out)
{
    // XCD swizzle: hardware round-robins blockIdx across 8 XCDs; remap so
    // each XCD walks contiguous (b, gi, ht) with ht fastest.
    int lid = (blockIdx.x & 7) * (NBLK2 / 8) + (blockIdx.x >> 3);
    int b   = lid / (GRP * 48);
    int rem = lid - b * (GRP * 48);
    int gi  = rem / 48;
    int ht  = rem - gi * 48;

    int tid = threadIdx.x;
    int cc  = tid % 192;          // output column
    int rl  = tid / 192;          // 0..3
    int r   = ht * 4 + rl;        // output row

    int h  = r >> 1, s1 = r & 1;
    int w  = cc >> 1, s2 = cc & 1;
    int o16 = gi * 4 + s1 * 2 + s2;

    size_t obase = ((size_t)b * 32 + o16) * HW + (size_t)h * WDIM + w;
    float ox = off[obase];
    float oy = off[obase + (size_t)16 * HW];

    float ix = fminf(fmaxf((float)w + ox, 0.0f), (float)(WDIM - 1));
    float iy = fminf(fmaxf((float)h + oy, 0.0f), (float)(HDIM - 1));
    float x0f = floorf(ix), y0f = floorf(iy);
    float wx = ix - x0f,   wy = iy - y0f;
    int x0 = (int)x0f, y0 = (int)y0f;
    int x1 = min(x0 + 1, WDIM - 1);
    int y1 = min(y0 + 1, HDIM - 1);

    float w00 = (1.0f - wy) * (1.0f - wx);
    float w01 = (1.0f - wy) * wx;
    float w10 = wy * (1.0f - wx);
    float w11 = wy * wx;

    int i00 = y0 * WDIM + x0, i01 = y0 * WDIM + x1;
    int i10 = y1 * WDIM + x0, i11 = y1 * WDIM + x1;

    const float* xp = x   + ((size_t)b * CDIM + (size_t)gi * CG) * HW;
    float*       op = out + (((size_t)b * CDIM + (size_t)gi * CG) * SH + r) * SW + cc;

    #pragma unroll 4
    for (int ch = 0; ch < CG; ++ch) {
        const float* p = xp + (size_t)ch * HW;
        float v = p[i00] * w00 + p[i01] * w01 + p[i10] * w10 + p[i11] * w11;
        __builtin_nontemporal_store(v, op + (size_t)ch * (SH * SW));
    }
}

extern "C" void kernel_launch(void* const* d_in, const int* in_sizes, int n_in,
                              void* d_out, int out_size, void* d_ws, size_t ws_size,
                              hipStream_t stream)
{
    const float* x     = (const float*)d_in[0];
    const float* w_off = (const float*)d_in[1];
    const float* b_off = (const float*)d_in[2];
    float* out = (float*)d_out;
    float* off = (float*)d_ws;   // needs 8*32*96*96*4 = 9.44 MB

    // Kernel 1: 73728 pixels / 64 px-per-block = 1152 blocks x 256 threads
    dysample_offset_kernel<<<(BDIM * HW) / 64, 256, 0, stream>>>(x, w_off, b_off, off);

    // Kernel 2: 1536 blocks x 768 threads (4 rows x 192 cols per block)
    dysample_sample_kernel<<<NBLK2, 768, 0, stream>>>(x, off, out);
}

// Round 2
// 400.900 us; speedup vs baseline: 1.4540x; 1.3371x over previous
//
#include <hip/hip_runtime.h>

#define BDIM 8
#define CDIM 256
#define HDIM 96
#define WDIM 96
#define GRP  4
#define CG   64          // channels per group
#define HC   32          // channels per sample-block (half group)
#define SH   192         // s*H
#define SW   192         // s*W
#define HW   (HDIM*WDIM) // 9216

// ---------------------------------------------------------------------------
// Kernel 1: per-pixel 256->32 dot product (the 1x1 conv offset head).
// K-split by 4: block = 256 threads = 64 pixels x 4 channel-slices.
// Unchanged from round 1 (isolating the kernel-2 change).
// ---------------------------------------------------------------------------
__global__ __launch_bounds__(256) void dysample_offset_kernel(
    const float* __restrict__ x,
    const float* __restrict__ w_off,
    const float* __restrict__ b_off,
    float* __restrict__ off)
{
    __shared__ float part[4][64][33];

    int tid = threadIdx.x;
    int pix = tid & 63;
    int ks  = __builtin_amdgcn_readfirstlane(tid >> 6);

    int p0  = blockIdx.x * 64;
    int b0  = p0 / HW;
    int hw0 = p0 - b0 * HW;
    int hw  = hw0 + pix;

    const float* xq = x + (size_t)b0 * CDIM * HW + (size_t)(ks * CG) * HW + hw;
    const float* wq = w_off + ks * CG;

    float acc[32];
    #pragma unroll
    for (int o = 0; o < 32; ++o) acc[o] = 0.0f;

    #pragma unroll 4
    for (int i = 0; i < CG; ++i) {
        float xv = xq[(size_t)i * HW];
        #pragma unroll
        for (int o = 0; o < 32; ++o)
            acc[o] = fmaf(xv, wq[o * CDIM + i], acc[o]);
    }

    #pragma unroll
    for (int o = 0; o < 32; ++o)
        part[ks][pix][o] = acc[o];

    __syncthreads();

    int pix2 = tid & 63;
    int og   = tid >> 6;
    float* op = off + ((size_t)b0 * 32) * HW + hw0 + pix2;
    #pragma unroll
    for (int j = 0; j < 8; ++j) {
        int o = og * 8 + j;
        float s = part[0][pix2][o] + part[1][pix2][o]
                + part[2][pix2][o] + part[3][pix2][o];
        op[(size_t)o * HW] = (s + b_off[o]) * 0.25f;
    }
}

// ---------------------------------------------------------------------------
// Kernel 2: bilinear sampling, LDS-staged.
// Block = 768 threads = one (b, gi, hc, ht): 4 output rows x 192 cols x 32 ch.
// Stage the 4 needed input rows x 32 channels (49 KB) into LDS once
// (coalesced float4), then per channel: 2 merged ds_read2_b32 (x0/x0+1
// word pairs, 2-way bank alias = free) + 4 FMA + 1 NT store. Global VMEM
// per output element drops 5 -> 1; only the mandatory 295 MB write stream
// remains. 49 KB LDS -> 2 blocks/CU (24 waves): staging of one block
// overlaps compute of the other.
// Clamp-at-95 handled by wx==0 / wy==0 exact-zero weights (read the
// neighbor word anyway; array padded). Never-taken global fallback keeps
// correctness if an offset ever leaves the 4-row window.
// ---------------------------------------------------------------------------
#define NBLK2 (BDIM * GRP * 2 * 48)   // 3072; % 8 == 0 -> simple swizzle ok
__global__ __launch_bounds__(768, 1) void dysample_sample_kernel(
    const float* __restrict__ x,
    const float* __restrict__ off,
    float* __restrict__ out)
{
    __shared__ __align__(16) float lds[HC * 384 + 4];   // 49 168 B

    // XCD-bijective swizzle: each XCD walks contiguous lids (ht fastest ->
    // neighboring h-tiles share staged rows in that XCD's L2).
    int lid = (blockIdx.x & 7) * (NBLK2 / 8) + (blockIdx.x >> 3);
    int ht  = lid % 48;
    int t1  = lid / 48;
    int hc  = t1 & 1;          // which 32-channel half of the group
    int t2  = t1 >> 1;
    int gi  = t2 & 3;
    int b   = t2 >> 2;

    int tid = threadIdx.x;
    int ylo = 2 * ht - 1;      // first row of the 4-row staging window

    // ---- stage: 32 ch x 4 rows x 96 cols = 3072 float4, 4 per thread ----
    const float* xg = x + ((size_t)b * CDIM + gi * CG + hc * HC) * HW;
    float4 tmp[4];
    #pragma unroll
    for (int k = 0; k < 4; ++k) {
        int c   = tid + k * 768;
        int ch  = c / 96;              // 0..31
        int r96 = c - ch * 96;
        int j   = r96 / 24;            // row within window, 0..3
        int q   = r96 - j * 24;        // float4 within row, 0..23
        int ysrc = min(max(ylo + j, 0), HDIM - 1);
        tmp[k] = *(const float4*)(xg + (size_t)ch * HW + ysrc * WDIM + q * 4);
    }
    #pragma unroll
    for (int k = 0; k < 4; ++k) {
        int c = tid + k * 768;
        *(float4*)(&lds[c * 4]) = tmp[k];
    }
    __syncthreads();

    // ---- sample ----
    int cc = tid % 192;        // output column (wave-contiguous)
    int rl = tid / 192;        // 0..3
    int r  = ht * 4 + rl;      // output row

    int h  = r >> 1, s1 = r & 1;
    int w  = cc >> 1, s2 = cc & 1;
    int o16 = gi * 4 + s1 * 2 + s2;

    size_t obase = ((size_t)b * 32 + o16) * HW + (size_t)h * WDIM + w;
    float ox = off[obase];
    float oy = off[obase + (size_t)16 * HW];

    float ix = fminf(fmaxf((float)w + ox, 0.0f), (float)(WDIM - 1));
    float iy = fminf(fmaxf((float)h + oy, 0.0f), (float)(HDIM - 1));
    float x0f = floorf(ix), y0f = floorf(iy);
    float wx = ix - x0f,   wy = iy - y0f;
    int x0 = (int)x0f, y0 = (int)y0f;
    int y1 = min(y0 + 1, HDIM - 1);

    float w00 = (1.0f - wy) * (1.0f - wx);
    float w01 = (1.0f - wy) * wx;
    float w10 = wy * (1.0f - wx);
    float w11 = wy * wx;

    int i0 = y0 - ylo;         // row index inside staged window
    int i1 = y1 - ylo;

    float* op = out + (((size_t)b * CDIM + gi * CG + hc * HC) * SH + r) * SW + cc;

    if (i0 >= 0 && i1 <= 3) {
        // fast path: everything in LDS. x0==95 => wx==0 exactly, so the
        // (x0+1) word (next row / pad) is multiplied by 0.
        int a0 = i0 * WDIM + x0;
        int a1 = i1 * WDIM + x0;
        #pragma unroll 8
        for (int ch = 0; ch < HC; ++ch) {
            const float* p = &lds[ch * 384];
            float v = p[a0] * w00;
            v = fmaf(p[a0 + 1], w01, v);
            v = fmaf(p[a1],     w10, v);
            v = fmaf(p[a1 + 1], w11, v);
            __builtin_nontemporal_store(v, op + (size_t)ch * (SH * SW));
        }
    } else {
        // robustness fallback (offset left the 4-row window) — global gather
        int x1 = min(x0 + 1, WDIM - 1);
        int i00 = y0 * WDIM + x0, i01 = y0 * WDIM + x1;
        int i10 = y1 * WDIM + x0, i11 = y1 * WDIM + x1;
        #pragma unroll 4
        for (int ch = 0; ch < HC; ++ch) {
            const float* p = xg + (size_t)ch * HW;
            float v = p[i00] * w00 + p[i01] * w01 + p[i10] * w10 + p[i11] * w11;
            __builtin_nontemporal_store(v, op + (size_t)ch * (SH * SW));
        }
    }
}

extern "C" void kernel_launch(void* const* d_in, const int* in_sizes, int n_in,
                              void* d_out, int out_size, void* d_ws, size_t ws_size,
                              hipStream_t stream)
{
    const float* x     = (const float*)d_in[0];
    const float* w_off = (const float*)d_in[1];
    const float* b_off = (const float*)d_in[2];
    float* out = (float*)d_out;
    float* off = (float*)d_ws;   // needs 8*32*96*96*4 = 9.44 MB

    // Kernel 1: 73728 pixels / 64 px-per-block = 1152 blocks x 256 threads
    dysample_offset_kernel<<<(BDIM * HW) / 64, 256, 0, stream>>>(x, w_off, b_off, off);

    // Kernel 2: 3072 blocks x 768 threads (4 rows x 192 cols x 32 ch)
    dysample_sample_kernel<<<NBLK2, 768, 0, stream>>>(x, off, out);
}